// Round 7
// baseline (291.820 us; speedup 1.0000x reference)
//
#include <hip/hip_runtime.h>
#include <hip/hip_bf16.h>

#define L_SEQ 2048
#define D_HEAD 64
#define NHEADS 64   // B*H
#define QSCALE (0.125f * 1.44269504088896340736f)  // 1/sqrt(64) * log2(e)

typedef __attribute__((ext_vector_type(8))) __bf16 bf16x8;
typedef __attribute__((ext_vector_type(16))) float f32x16;

// Byte offset into a [rows][64] bf16 tile (128B rows), XOR-swizzled (G4).
__device__ __forceinline__ int swz(int row, int col) {
    int off = (row << 7) | (col << 1);
    return off ^ ((row & 7) << 4);
}
__device__ __forceinline__ bf16x8 read_frag(const char* lds, int row, int col) {
    return *reinterpret_cast<const bf16x8*>(lds + swz(row, col));
}

// 256-thread staging helpers
template <int ROWS>
__device__ __forceinline__ void stage_load(float4* regs, const float* src,
                                           int srcStride, int t) {
    int r0 = t >> 4, c4 = (t & 15) << 2;
#pragma unroll
    for (int i = 0; i < ROWS / 16; ++i)
        regs[i] = *reinterpret_cast<const float4*>(src + (size_t)(r0 + i * 16) * srcStride + c4);
}
template <int ROWS>
__device__ __forceinline__ void stage_write(char* lds, const float4* regs, int t,
                                            float scale) {
    int r0 = t >> 4, c4 = (t & 15) << 2;
#pragma unroll
    for (int i = 0; i < ROWS / 16; ++i) {
        float4 v = regs[i];
        union { __bf16 h[4]; unsigned long long u; } pk;
        pk.h[0] = (__bf16)(v.x * scale);
        pk.h[1] = (__bf16)(v.y * scale);
        pk.h[2] = (__bf16)(v.z * scale);
        pk.h[3] = (__bf16)(v.w * scale);
        *reinterpret_cast<unsigned long long*>(lds + swz(r0 + i * 16, c4)) = pk.u;
    }
}

// component-wise scaled bf16 pack+write
__device__ __forceinline__ void pack_write(char* lds, int row, int c4, float4 v,
                                           float4 sc) {
    union { __bf16 h[4]; unsigned long long u; } pk;
    pk.h[0] = (__bf16)(v.x * sc.x);
    pk.h[1] = (__bf16)(v.y * sc.y);
    pk.h[2] = (__bf16)(v.z * sc.z);
    pk.h[3] = (__bf16)(v.w * sc.w);
    *reinterpret_cast<unsigned long long*>(lds + swz(row, c4)) = pk.u;
}

__device__ __forceinline__ unsigned cvt_pk_bf16(float lo, float hi) {
    unsigned r;
    asm("v_cvt_pk_bf16_f32 %0, %1, %2" : "=v"(r) : "v"(lo), "v"(hi));
    return r;
}

// -------- Pass 1: invl[bh][q] = 1 / sum_k exp2(QSCALE*(Q.K)) ----------------
// (unchanged from round 5)
__global__ __launch_bounds__(256, 3) void attn_pass1(const float* __restrict__ Q,
                                                     const float* __restrict__ K,
                                                     float* __restrict__ invl) {
    __shared__ __align__(16) char lds[2][128 * 128];   // 2 x 16KB K buffers
    __shared__ float red[4][64];

    int bid = blockIdx.x;
    int sb = (bid & 7) * 256 + (bid >> 3);   // bijective XCD swizzle (2048 = 8*256)
    int bh = sb >> 5;
    int q0 = (sb & 31) << 6;
    const float* Qh = Q + (size_t)bh * L_SEQ * D_HEAD + (size_t)q0 * D_HEAD;
    const float* Kh = K + (size_t)bh * L_SEQ * D_HEAD;

    int t = threadIdx.x, lane = t & 63, w = t >> 6;
    int hl = lane >> 5, l31 = lane & 31;

    {
        float4 qreg[4];
        stage_load<64>(qreg, Qh, D_HEAD, t);
        stage_write<64>(lds[0], qreg, t, QSCALE);
    }
    __syncthreads();
    bf16x8 qfrag[2][4];
#pragma unroll
    for (int qb = 0; qb < 2; ++qb)
#pragma unroll
        for (int m = 0; m < 4; ++m)
            qfrag[qb][m] = read_frag(lds[0], qb * 32 + l31, m * 16 + hl * 8);
    __syncthreads();
    {
        float4 kreg[8];
        stage_load<128>(kreg, Kh, D_HEAD, t);
        stage_write<128>(lds[0], kreg, t, 1.0f);
    }
    __syncthreads();

    float lsum[2][16];
#pragma unroll
    for (int qb = 0; qb < 2; ++qb)
#pragma unroll
        for (int r = 0; r < 16; ++r) lsum[qb][r] = 0.f;

    for (int k0 = 0; k0 < L_SEQ; k0 += 128) {
        int c = (k0 >> 7) & 1;
        const char* kcur = c ? lds[1] : lds[0];
        char* knext = c ? lds[0] : lds[1];

        int nk0 = (k0 + 128) & (L_SEQ - 1);
        float4 kreg[8];
        stage_load<128>(kreg, Kh + (size_t)nk0 * D_HEAD, D_HEAD, t);

        bf16x8 kfr[4];
#pragma unroll
        for (int m = 0; m < 4; ++m)
            kfr[m] = read_frag(kcur, w * 32 + l31, m * 16 + hl * 8);

        f32x16 s[2];
#pragma unroll
        for (int qb = 0; qb < 2; ++qb)
#pragma unroll
            for (int r = 0; r < 16; ++r) s[qb][r] = 0.f;

        __builtin_amdgcn_s_setprio(1);
#pragma unroll
        for (int m = 0; m < 4; ++m) {
            s[0] = __builtin_amdgcn_mfma_f32_32x32x16_bf16(qfrag[0][m], kfr[m], s[0], 0, 0, 0);
            s[1] = __builtin_amdgcn_mfma_f32_32x32x16_bf16(qfrag[1][m], kfr[m], s[1], 0, 0, 0);
        }
        __builtin_amdgcn_s_setprio(0);

#pragma unroll
        for (int qb = 0; qb < 2; ++qb)
#pragma unroll
            for (int r = 0; r < 16; ++r)
                lsum[qb][r] += __builtin_amdgcn_exp2f(s[qb][r]);

        stage_write<128>(knext, kreg, t, 1.0f);
        __syncthreads();   // single barrier per iter (double-buffered)
    }

#pragma unroll
    for (int qb = 0; qb < 2; ++qb)
#pragma unroll
        for (int r = 0; r < 16; ++r) {
            float v = lsum[qb][r];
            v += __shfl_xor(v, 1);
            v += __shfl_xor(v, 2);
            v += __shfl_xor(v, 4);
            v += __shfl_xor(v, 8);
            v += __shfl_xor(v, 16);
            lsum[qb][r] = v;
        }
    if (l31 == 0) {
#pragma unroll
        for (int qb = 0; qb < 2; ++qb)
#pragma unroll
            for (int r = 0; r < 16; ++r)
                red[w][qb * 32 + (r & 3) + 8 * (r >> 2) + 4 * hl] = lsum[qb][r];
    }
    __syncthreads();
    if (t < 64) {
        float ssum = red[0][t] + red[1][t] + red[2][t] + red[3][t];
        invl[(size_t)bh * L_SEQ + q0 + t] = 1.0f / ssum;
    }
}

// -------- Pass 2: Out[d, k-tile] = sum_q (V[d,q]*invl[q]) * exp2(s[q,k]) ----
// 256 threads / 4 waves = (wq 2) x (wk 2). k-tile 128; each wave owns 64
// k-cols (kfrag[2][4] in regs) and processes only its 32-q half of each
// 64-q step: 8 LDS frag reads -> 16 MFMA (1:2). Partial accs combined via
// a 32KB LDS exchange at the end. 3 blocks/CU.
__global__ __launch_bounds__(256, 3) void attn_pass2(const float* __restrict__ Q,
                                                     const float* __restrict__ K,
                                                     const float* __restrict__ V,
                                                     const float* __restrict__ invl,
                                                     float* __restrict__ out) {
    __shared__ __align__(16) char lds[49152];
    // layout: [0,16K) K resident; [16K,24K) Q0; [24K,32K) V0;
    //         [32K,40K) Q1; [40K,48K) V1

    int bid = blockIdx.x;
    int sb = (bid & 7) * 128 + (bid >> 3);   // bijective XCD swizzle (1024 = 8*128)
    int bh = sb >> 4;
    int k0 = (sb & 15) << 7;                 // 16 k-tiles of 128 per head
    const float* Qh = Q + (size_t)bh * L_SEQ * D_HEAD;
    const float* Kh = K + (size_t)bh * L_SEQ * D_HEAD + (size_t)k0 * D_HEAD;
    const float* Vh = V + (size_t)bh * D_HEAD * L_SEQ;
    const float* il = invl + (size_t)bh * L_SEQ;
    float* Oh = out + (size_t)bh * D_HEAD * L_SEQ;

    int t = threadIdx.x, lane = t & 63, w = t >> 6;
    int wq = w >> 1, wk = w & 1;
    int hl = lane >> 5, l31 = lane & 31;
    int r0 = t >> 4;          // staging row 0..15
    int c4 = (t & 15) << 2;   // staging col group

    // prologue A: stage K[128][64] -> bf16 LDS, frags -> regs
    {
        float4 kreg[8];
        stage_load<128>(kreg, Kh, D_HEAD, t);
        stage_write<128>(lds, kreg, t, 1.0f);
    }
    __syncthreads();
    bf16x8 kfrag[2][4];
#pragma unroll
    for (int kb = 0; kb < 2; ++kb)
#pragma unroll
        for (int m = 0; m < 4; ++m)
            kfrag[kb][m] = read_frag(lds, wk * 64 + kb * 32 + l31, m * 16 + hl * 8);

    // prologue B: stage Q0 / V0 (V scaled by invl)
    {
        float4 qreg[4], vreg[4];
        stage_load<64>(qreg, Qh, D_HEAD, t);
        stage_load<64>(vreg, Vh, L_SEQ, t);
        float4 iv = *reinterpret_cast<const float4*>(il + c4);
        float4 qs = make_float4(QSCALE, QSCALE, QSCALE, QSCALE);
#pragma unroll
        for (int i = 0; i < 4; ++i) {
            pack_write(lds + 16384, r0 + i * 16, c4, qreg[i], qs);
            pack_write(lds + 24576, r0 + i * 16, c4, vreg[i], iv);
        }
    }
    __syncthreads();

    f32x16 acc[2][2];   // [db][kb] partial over this wave's q-half
#pragma unroll
    for (int db = 0; db < 2; ++db)
#pragma unroll
        for (int kb = 0; kb < 2; ++kb)
#pragma unroll
            for (int r = 0; r < 16; ++r) acc[db][kb][r] = 0.f;

    for (int q0 = 0; q0 < L_SEQ; q0 += 64) {
        int c = (q0 >> 6) & 1;
        const char* qcur = lds + (c ? 32768 : 16384);
        const char* vcur = lds + (c ? 40960 : 24576);
        char* qnext = lds + (c ? 16384 : 32768);
        char* vnext = lds + (c ? 24576 : 40960);

        // prefetch next Q/V tiles (wrapped on last iter)
        int nq0 = (q0 + 64) & (L_SEQ - 1);
        float4 qreg[4], vreg[4];
        stage_load<64>(qreg, Qh + (size_t)nq0 * D_HEAD, D_HEAD, t);
        stage_load<64>(vreg, Vh + nq0, L_SEQ, t);

        // S = Q.K^T for this wave's 32-q half x 64 k-cols
        f32x16 s[2];
#pragma unroll
        for (int kb = 0; kb < 2; ++kb)
#pragma unroll
            for (int r = 0; r < 16; ++r) s[kb][r] = 0.f;

        __builtin_amdgcn_s_setprio(1);
#pragma unroll
        for (int m = 0; m < 4; ++m) {
            bf16x8 afr = read_frag(qcur, wq * 32 + l31, m * 16 + hl * 8);
            s[0] = __builtin_amdgcn_mfma_f32_32x32x16_bf16(afr, kfrag[0][m], s[0], 0, 0, 0);
            s[1] = __builtin_amdgcn_mfma_f32_32x32x16_bf16(afr, kfrag[1][m], s[1], 0, 0, 0);
        }
        __builtin_amdgcn_s_setprio(0);

        // P = exp2(s) -> bf16 frag words in-register (invl folded into V)
        bf16x8 pfrag[2][2];
#pragma unroll
        for (int kb = 0; kb < 2; ++kb) {
            float p[16];
#pragma unroll
            for (int r = 0; r < 16; ++r) p[r] = __builtin_amdgcn_exp2f(s[kb][r]);
            unsigned wA[4], wB[4];
#pragma unroll
            for (int g = 0; g < 4; ++g) {
                wA[g] = cvt_pk_bf16(p[4 * g + 0], p[4 * g + 1]);
                wB[g] = cvt_pk_bf16(p[4 * g + 2], p[4 * g + 3]);
            }
#pragma unroll
            for (int mm = 0; mm < 2; ++mm) {
                unsigned a0 = wA[2 * mm], b0 = wA[2 * mm + 1];
                unsigned a1 = wB[2 * mm], b1 = wB[2 * mm + 1];
                asm volatile("v_permlane32_swap_b32 %0, %1" : "+v"(a0), "+v"(b0));
                asm volatile("v_permlane32_swap_b32 %0, %1" : "+v"(a1), "+v"(b1));
                union { unsigned u[4]; bf16x8 v; } pk;
                pk.u[0] = a0;
                pk.u[1] = a1;
                pk.u[2] = b0;
                pk.u[3] = b1;
                pfrag[kb][mm] = pk.v;
            }
        }

        // PV: acc[d,k] += V'[d, q16] @ P[q16, k]  (vfr reused for both kb)
        __builtin_amdgcn_s_setprio(1);
#pragma unroll
        for (int mm = 0; mm < 2; ++mm)
#pragma unroll
            for (int db = 0; db < 2; ++db) {
                bf16x8 vfr = read_frag(vcur, db * 32 + l31, wq * 32 + mm * 16 + hl * 8);
#pragma unroll
                for (int kb = 0; kb < 2; ++kb)
                    acc[db][kb] = __builtin_amdgcn_mfma_f32_32x32x16_bf16(
                        vfr, pfrag[kb][mm], acc[db][kb], 0, 0, 0);
            }
        __builtin_amdgcn_s_setprio(0);

        // stage next Q/V
        {
            float4 ivn = *reinterpret_cast<const float4*>(il + nq0 + c4);
            float4 qs = make_float4(QSCALE, QSCALE, QSCALE, QSCALE);
#pragma unroll
            for (int i = 0; i < 4; ++i) {
                pack_write(qnext, r0 + i * 16, c4, qreg[i], qs);
                pack_write(vnext, r0 + i * 16, c4, vreg[i], ivn);
            }
        }
        __syncthreads();   // single barrier per q-step
    }

    // epilogue: combine wq partials via LDS, wq=0 stores
    __syncthreads();
    float* exf = reinterpret_cast<float*>(lds + 16384);   // 32 KB exchange
    if (wq == 1) {
#pragma unroll
        for (int db = 0; db < 2; ++db)
#pragma unroll
            for (int kb = 0; kb < 2; ++kb)
#pragma unroll
                for (int r = 0; r < 16; ++r)
                    exf[(((wk * 2 + db) * 2 + kb) * 16 + r) * 64 + lane] = acc[db][kb][r];
    }
    __syncthreads();
    if (wq == 0) {
#pragma unroll
        for (int db = 0; db < 2; ++db)
#pragma unroll
            for (int kb = 0; kb < 2; ++kb)
#pragma unroll
                for (int r = 0; r < 16; ++r) {
                    float v = acc[db][kb][r] +
                              exf[(((wk * 2 + db) * 2 + kb) * 16 + r) * 64 + lane];
                    int d = db * 32 + (r & 3) + 8 * (r >> 2) + 4 * hl;
                    int k = k0 + wk * 64 + kb * 32 + l31;
                    Oh[(size_t)d * L_SEQ + k] = v;
                }
    }
}

extern "C" void kernel_launch(void* const* d_in, const int* in_sizes, int n_in,
                              void* d_out, int out_size, void* d_ws, size_t ws_size,
                              hipStream_t stream) {
    const float* Q = (const float*)d_in[0];
    const float* K = (const float*)d_in[1];
    const float* V = (const float*)d_in[2];
    float* invl = (float*)d_ws;          // NHEADS * L_SEQ floats = 512 KB
    float* out = (float*)d_out;

    attn_pass1<<<dim3(NHEADS * (L_SEQ / 64)), dim3(256), 0, stream>>>(Q, K, invl);
    attn_pass2<<<dim3(NHEADS * (L_SEQ / 128)), dim3(256), 0, stream>>>(Q, K, V, invl, out);
}

// Round 8
// 139.639 us; speedup vs baseline: 2.0898x; 2.0898x over previous
//
#include <hip/hip_runtime.h>
#include <hip/hip_bf16.h>

#define L_SEQ 2048
#define D_HEAD 64
#define NHEADS 64   // B*H
#define QSCALE (0.125f * 1.44269504088896340736f)  // 1/sqrt(64) * log2(e)

typedef __attribute__((ext_vector_type(8))) __bf16 bf16x8;
typedef __attribute__((ext_vector_type(16))) float f32x16;

// [rows][64] bf16 tile (128B rows), XOR-swizzled (G4).
__device__ __forceinline__ int swz(int row, int col) {
    int off = (row << 7) | (col << 1);
    return off ^ ((row & 7) << 4);
}
__device__ __forceinline__ bf16x8 read_frag(const char* lds, int row, int col) {
    return *reinterpret_cast<const bf16x8*>(lds + swz(row, col));
}
__device__ __forceinline__ void pack_write(char* lds, int row, int c4, float4 v,
                                           float4 sc) {
    union { __bf16 h[4]; unsigned long long u; } pk;
    pk.h[0] = (__bf16)(v.x * sc.x);
    pk.h[1] = (__bf16)(v.y * sc.y);
    pk.h[2] = (__bf16)(v.z * sc.z);
    pk.h[3] = (__bf16)(v.w * sc.w);
    *reinterpret_cast<unsigned long long*>(lds + swz(row, c4)) = pk.u;
}

// [64][128] bf16 tile (256B rows), 16-row XOR (2-way instead of 4-way on reads)
__device__ __forceinline__ int swz128(int row, int col) {
    int off = (row << 8) | (col << 1);
    return off ^ ((row & 15) << 4);
}
__device__ __forceinline__ bf16x8 read_frag128(const char* lds, int row, int col) {
    return *reinterpret_cast<const bf16x8*>(lds + swz128(row, col));
}
__device__ __forceinline__ void pack_write128(char* lds, int row, int c4, float4 v,
                                              float4 sc) {
    union { __bf16 h[4]; unsigned long long u; } pk;
    pk.h[0] = (__bf16)(v.x * sc.x);
    pk.h[1] = (__bf16)(v.y * sc.y);
    pk.h[2] = (__bf16)(v.z * sc.z);
    pk.h[3] = (__bf16)(v.w * sc.w);
    *reinterpret_cast<unsigned long long*>(lds + swz128(row, c4)) = pk.u;
}

__device__ __forceinline__ unsigned cvt_pk_bf16(float lo, float hi) {
    unsigned r;
    asm("v_cvt_pk_bf16_f32 %0, %1, %2" : "=v"(r) : "v"(lo), "v"(hi));
    return r;
}

// -------- Pass 1: invl[bh][q] = 1 / sum_k exp2(QSCALE*(Q.K)) ----------------
// q-tile 128, grid 64*16=1024 @ (256,4) -> 1024 slots = ONE clean batch.
// 4 waves = wq2 x wk2; Q-frags (64-q half) in regs; K streamed 64/step dbuf.
__global__ __launch_bounds__(256, 4) void attn_pass1(const float* __restrict__ Q,
                                                     const float* __restrict__ K,
                                                     float* __restrict__ invl) {
    __shared__ __align__(16) char lds[16384];   // Q stage, then 2 x 8KB K dbuf
    __shared__ float red[2][128];

    int bid = blockIdx.x;
    int sb = (bid & 7) * 128 + (bid >> 3);   // bijective XCD swizzle (1024 = 8*128)
    int bh = sb >> 4;
    int q0 = (sb & 15) << 7;
    const float* Qh = Q + (size_t)bh * L_SEQ * D_HEAD + (size_t)q0 * D_HEAD;
    const float* Kh = K + (size_t)bh * L_SEQ * D_HEAD;

    int t = threadIdx.x, lane = t & 63, w = t >> 6;
    int wq = w >> 1, wk = w & 1;
    int hl = lane >> 5, l31 = lane & 31;
    int r0 = t >> 4;          // 0..15
    int c4 = (t & 15) << 2;

    // stage Q[128][64] (rows 0..127 across the 16KB region)
    {
        float4 qs = make_float4(QSCALE, QSCALE, QSCALE, QSCALE);
#pragma unroll
        for (int i = 0; i < 8; ++i) {
            float4 v = *reinterpret_cast<const float4*>(Qh + (size_t)(r0 + i * 16) * D_HEAD + c4);
            pack_write(lds, r0 + i * 16, c4, v, qs);
        }
    }
    __syncthreads();
    bf16x8 qfrag[2][4];
#pragma unroll
    for (int qb = 0; qb < 2; ++qb)
#pragma unroll
        for (int m = 0; m < 4; ++m)
            qfrag[qb][m] = read_frag(lds, wq * 64 + qb * 32 + l31, m * 16 + hl * 8);
    __syncthreads();
    // stage K tile 0 into buf0
    {
        float4 one = make_float4(1.f, 1.f, 1.f, 1.f);
#pragma unroll
        for (int i = 0; i < 4; ++i) {
            float4 v = *reinterpret_cast<const float4*>(Kh + (size_t)(r0 + i * 16) * D_HEAD + c4);
            pack_write(lds, r0 + i * 16, c4, v, one);
        }
    }
    __syncthreads();

    float lsum[2][16];
#pragma unroll
    for (int qb = 0; qb < 2; ++qb)
#pragma unroll
        for (int r = 0; r < 16; ++r) lsum[qb][r] = 0.f;

    for (int k0 = 0; k0 < L_SEQ; k0 += 64) {
        int c = (k0 >> 6) & 1;
        const char* kcur = lds + (c ? 8192 : 0);
        char* knext = lds + (c ? 0 : 8192);

        int nk0 = (k0 + 64) & (L_SEQ - 1);
        float4 kreg[4];
#pragma unroll
        for (int i = 0; i < 4; ++i)
            kreg[i] = *reinterpret_cast<const float4*>(Kh + (size_t)(nk0 + r0 + i * 16) * D_HEAD + c4);

        bf16x8 kfr[4];
#pragma unroll
        for (int m = 0; m < 4; ++m)
            kfr[m] = read_frag(kcur, wk * 32 + l31, m * 16 + hl * 8);

        __builtin_amdgcn_s_setprio(1);
#pragma unroll
        for (int qb = 0; qb < 2; ++qb) {
            f32x16 s;
#pragma unroll
            for (int r = 0; r < 16; ++r) s[r] = 0.f;
#pragma unroll
            for (int m = 0; m < 4; ++m)
                s = __builtin_amdgcn_mfma_f32_32x32x16_bf16(qfrag[qb][m], kfr[m], s, 0, 0, 0);
#pragma unroll
            for (int r = 0; r < 16; ++r)
                lsum[qb][r] += __builtin_amdgcn_exp2f(s[r]);
        }
        __builtin_amdgcn_s_setprio(0);

        {
            float4 one = make_float4(1.f, 1.f, 1.f, 1.f);
#pragma unroll
            for (int i = 0; i < 4; ++i)
                pack_write(knext, r0 + i * 16, c4, kreg[i], one);
        }
        __syncthreads();   // single barrier per step (double-buffered)
    }

    // reduce over this wave's 32 k-lanes
#pragma unroll
    for (int qb = 0; qb < 2; ++qb)
#pragma unroll
        for (int r = 0; r < 16; ++r) {
            float v = lsum[qb][r];
            v += __shfl_xor(v, 1);
            v += __shfl_xor(v, 2);
            v += __shfl_xor(v, 4);
            v += __shfl_xor(v, 8);
            v += __shfl_xor(v, 16);
            lsum[qb][r] = v;
        }
    if (l31 == 0) {
#pragma unroll
        for (int qb = 0; qb < 2; ++qb)
#pragma unroll
            for (int r = 0; r < 16; ++r)
                red[wk][wq * 64 + qb * 32 + (r & 3) + 8 * (r >> 2) + 4 * hl] = lsum[qb][r];
    }
    __syncthreads();
    if (t < 128) {
        float ssum = red[0][t] + red[1][t];
        invl[(size_t)bh * L_SEQ + q0 + t] = 1.0f / ssum;
    }
}

// -------- Pass 2: Out[d, k-tile] = sum_q (V[d,q]*invl[q]) * exp2(s[q,k]) ----
// Round-5 wave layout (8 waves x 32 k-cols, kfrag regs, acc[2]) but q-step
// 128: 16 steps, halved barrier/staging fixed cost. Staggered staging
// (Q-issue top, V-issue mid) to bound VGPR. Grid 512 @ 2 blocks/CU = clean.
__global__ __launch_bounds__(512, 4) void attn_pass2(const float* __restrict__ Q,
                                                     const float* __restrict__ K,
                                                     const float* __restrict__ V,
                                                     const float* __restrict__ invl,
                                                     float* __restrict__ out) {
    __shared__ __align__(16) char lds[65536];
    // buf c at c*32768: Q[128][64] bf16 (16KB) + V[64][128] bf16 (16KB)

    int bid = blockIdx.x;
    int sb = (bid & 7) * 64 + (bid >> 3);    // bijective XCD swizzle (512 = 8*64)
    int bh = sb >> 3;
    int k0 = (sb & 7) << 8;
    const float* Qh = Q + (size_t)bh * L_SEQ * D_HEAD;
    const float* Kh = K + (size_t)bh * L_SEQ * D_HEAD + (size_t)k0 * D_HEAD;
    const float* Vh = V + (size_t)bh * D_HEAD * L_SEQ;
    const float* il = invl + (size_t)bh * L_SEQ;
    float* Oh = out + (size_t)bh * D_HEAD * L_SEQ;

    int t = threadIdx.x, lane = t & 63, w = t >> 6;    // w 0..7
    int hl = lane >> 5, l31 = lane & 31;
    int r0 = t >> 4;          // 0..31 (Q/K staging row)
    int c4 = (t & 15) << 2;
    int r0v = t >> 5;         // 0..15 (V staging row)
    int c8 = (t & 31) << 2;   // V staging col group (0..124)

    // prologue A: stage K[256][64], read kfrags
    {
        float4 one = make_float4(1.f, 1.f, 1.f, 1.f);
#pragma unroll
        for (int i = 0; i < 8; ++i) {
            float4 v = *reinterpret_cast<const float4*>(Kh + (size_t)(r0 + i * 32) * D_HEAD + c4);
            pack_write(lds, r0 + i * 32, c4, v, one);
        }
    }
    __syncthreads();
    bf16x8 kfrag[4];
#pragma unroll
    for (int m = 0; m < 4; ++m)
        kfrag[m] = read_frag(lds, w * 32 + l31, m * 16 + hl * 8);
    __syncthreads();

    // prologue B: stage Q0[128][64] and V0[64][128] (V scaled by invl)
    {
        float4 qs = make_float4(QSCALE, QSCALE, QSCALE, QSCALE);
#pragma unroll
        for (int i = 0; i < 4; ++i) {
            float4 v = *reinterpret_cast<const float4*>(Qh + (size_t)(r0 + i * 32) * D_HEAD + c4);
            pack_write(lds, r0 + i * 32, c4, v, qs);
        }
        float4 iv = *reinterpret_cast<const float4*>(il + c8);
#pragma unroll
        for (int i = 0; i < 4; ++i) {
            float4 v = *reinterpret_cast<const float4*>(Vh + (size_t)(r0v + i * 16) * L_SEQ + c8);
            pack_write128(lds + 16384, r0v + i * 16, c8, v, iv);
        }
    }
    __syncthreads();

    f32x16 acc[2];
#pragma unroll
    for (int db = 0; db < 2; ++db)
#pragma unroll
        for (int r = 0; r < 16; ++r) acc[db][r] = 0.f;

    for (int q0 = 0; q0 < L_SEQ; q0 += 128) {
        int c = (q0 >> 7) & 1;
        const char* qcur = lds + (c ? 32768 : 0);
        const char* vcur = qcur + 16384;
        char* qnext = lds + (c ? 0 : 32768);
        char* vnext = qnext + 16384;

        int nq0 = (q0 + 128) & (L_SEQ - 1);
        // issue next-Q loads (cover under qq=0,1)
        float4 qreg[4];
#pragma unroll
        for (int i = 0; i < 4; ++i)
            qreg[i] = *reinterpret_cast<const float4*>(Qh + (size_t)(nq0 + r0 + i * 32) * D_HEAD + c4);
        float4 vreg[4], ivn;

#pragma unroll
        for (int qq = 0; qq < 4; ++qq) {
            // S = Q.K^T (A from LDS, B from regs)
            f32x16 s;
#pragma unroll
            for (int r = 0; r < 16; ++r) s[r] = 0.f;
            __builtin_amdgcn_s_setprio(1);
#pragma unroll
            for (int m = 0; m < 4; ++m) {
                bf16x8 afr = read_frag(qcur, qq * 32 + l31, m * 16 + hl * 8);
                s = __builtin_amdgcn_mfma_f32_32x32x16_bf16(afr, kfrag[m], s, 0, 0, 0);
            }
            __builtin_amdgcn_s_setprio(0);

            // P = exp2(s) -> bf16 frag words in-register (invl folded into V)
            unsigned wA[4], wB[4];
#pragma unroll
            for (int g = 0; g < 4; ++g) {
                wA[g] = cvt_pk_bf16(__builtin_amdgcn_exp2f(s[4 * g + 0]),
                                    __builtin_amdgcn_exp2f(s[4 * g + 1]));
                wB[g] = cvt_pk_bf16(__builtin_amdgcn_exp2f(s[4 * g + 2]),
                                    __builtin_amdgcn_exp2f(s[4 * g + 3]));
            }
            bf16x8 pfrag[2];
#pragma unroll
            for (int mm = 0; mm < 2; ++mm) {
                unsigned a0 = wA[2 * mm], b0 = wA[2 * mm + 1];
                unsigned a1 = wB[2 * mm], b1 = wB[2 * mm + 1];
                asm volatile("v_permlane32_swap_b32 %0, %1" : "+v"(a0), "+v"(b0));
                asm volatile("v_permlane32_swap_b32 %0, %1" : "+v"(a1), "+v"(b1));
                union { unsigned u[4]; bf16x8 v; } pk;
                pk.u[0] = a0;
                pk.u[1] = a1;
                pk.u[2] = b0;
                pk.u[3] = b1;
                pfrag[mm] = pk.v;
            }

            // PV: acc[d,k] += V'[d, q16] @ P[q16, k]
            __builtin_amdgcn_s_setprio(1);
#pragma unroll
            for (int mm = 0; mm < 2; ++mm)
#pragma unroll
                for (int db = 0; db < 2; ++db) {
                    bf16x8 vfr = read_frag128(vcur, db * 32 + l31, qq * 32 + mm * 16 + hl * 8);
                    acc[db] = __builtin_amdgcn_mfma_f32_32x32x16_bf16(
                        vfr, pfrag[mm], acc[db], 0, 0, 0);
                }
            __builtin_amdgcn_s_setprio(0);

            if (qq == 1) {
                // write next-Q; issue next-V loads (cover under qq=2,3)
                float4 qs = make_float4(QSCALE, QSCALE, QSCALE, QSCALE);
#pragma unroll
                for (int i = 0; i < 4; ++i)
                    pack_write(qnext, r0 + i * 32, c4, qreg[i], qs);
#pragma unroll
                for (int i = 0; i < 4; ++i)
                    vreg[i] = *reinterpret_cast<const float4*>(Vh + (size_t)(r0v + i * 16) * L_SEQ + nq0 + c8);
                ivn = *reinterpret_cast<const float4*>(il + nq0 + c8);
            }
        }
#pragma unroll
        for (int i = 0; i < 4; ++i)
            pack_write128(vnext, r0v + i * 16, c8, vreg[i], ivn);
        __syncthreads();   // single barrier per 128-q step
    }

#pragma unroll
    for (int db = 0; db < 2; ++db)
#pragma unroll
        for (int r = 0; r < 16; ++r) {
            int d = db * 32 + (r & 3) + 8 * (r >> 2) + 4 * hl;
            int k = k0 + w * 32 + l31;
            Oh[(size_t)d * L_SEQ + k] = acc[db][r];
        }
}

extern "C" void kernel_launch(void* const* d_in, const int* in_sizes, int n_in,
                              void* d_out, int out_size, void* d_ws, size_t ws_size,
                              hipStream_t stream) {
    const float* Q = (const float*)d_in[0];
    const float* K = (const float*)d_in[1];
    const float* V = (const float*)d_in[2];
    float* invl = (float*)d_ws;          // NHEADS * L_SEQ floats = 512 KB
    float* out = (float*)d_out;

    attn_pass1<<<dim3(NHEADS * (L_SEQ / 128)), dim3(256), 0, stream>>>(Q, K, invl);
    attn_pass2<<<dim3(NHEADS * (L_SEQ / 256)), dim3(512), 0, stream>>>(Q, K, V, invl, out);
}